// Round 1
// baseline (201.756 us; speedup 1.0000x reference)
//
#include <hip/hip_runtime.h>
#include <stdint.h>

// out[b,s,n] = int32(sum_k x[b,s,k]*w[n,k]) * (scale_i*scale_w[n]) + bias[n]
// Inputs materialized as int32; pack to int8 in d_ws, then i8 MFMA GEMM.
// GEMM: 256x256 tile, BK=128, 8 waves (2Mx4N), 128 KiB LDS double-buffer,
// depth-2 tile prefetch with counted vmcnt(8) (never drained in main loop),
// raw s_barrier (no vmcnt drain), setprio around MFMA clusters, 2D XCD swizzle.
#define M_DIM 8192
#define N_DIM 4096
#define K_DIM 1024
#define BK    128
#define NT    (K_DIM / BK)   // 8 K-tiles

using i32x4 = __attribute__((ext_vector_type(4))) int;

// ---- fused pack pass: int32 (low byte) -> int8, 16 ints per thread ----
// blocks [0, 2048): X (8.4M ints); blocks [2048, 3072): W (4.2M ints)
__global__ __launch_bounds__(256) void pack_both(const int* __restrict__ X32,
                                                 const int* __restrict__ W32,
                                                 int* __restrict__ Xp,
                                                 int* __restrict__ Wp) {
    int b = blockIdx.x;
    const int4* s4;
    int4* d4;
    int u;
    if (b < 2048) {            // X: 2097152 packed dwords / 4 per thread
        u  = b * 256 + threadIdx.x;
        s4 = (const int4*)X32;
        d4 = (int4*)Xp;
    } else {                   // W: 1048576 packed dwords / 4 per thread
        u  = (b - 2048) * 256 + threadIdx.x;
        s4 = (const int4*)W32;
        d4 = (int4*)Wp;
    }
    int4 o;
    #pragma unroll
    for (int i = 0; i < 4; ++i) {
        int4 v = s4[u * 4 + i];
        ((int*)&o)[i] = (v.x & 0xFF) | ((v.y & 0xFF) << 8) |
                        ((v.z & 0xFF) << 16) | (v.w << 24);
    }
    d4[u] = o;
}

// async global->LDS, 16B per lane. LDS dest is wave-uniform base + lane*16.
__device__ __forceinline__ void cp16_async(const void* g, void* l) {
    __builtin_amdgcn_global_load_lds(
        (const __attribute__((address_space(1))) void*)g,
        (__attribute__((address_space(3))) void*)l,
        16, 0, 0);
}

__global__ __launch_bounds__(512, 2) void i8gemm_dequant(
    const int8_t* __restrict__ X,        // [M, K] packed int8
    const int8_t* __restrict__ W,        // [N, K] packed int8
    const float*  __restrict__ scale_i,  // [1]
    const float*  __restrict__ scale_w,  // [N]
    const float*  __restrict__ bias,     // [N]
    float*        __restrict__ out)      // [M, N]
{
    // [buf][A|B][256 rows x 128 B] = 2*2*32 KB = 128 KiB
    __shared__ int8_t lds[2][2][256 * BK];

    const int t     = threadIdx.x;
    const int lane  = t & 63;
    const int wave  = t >> 6;      // 0..7
    const int waveM = wave >> 2;   // 0..1 -> which 128-row half of the tile
    const int waveN = wave & 3;    // 0..3 -> which 64-col quarter

    // 2D XCD-aware swizzle: 512 blocks -> 8 XCDs, each gets an 8x8 tile chunk
    // (2 MB of A rows + 2 MB of B rows fits the XCD's 4 MB L2).
    const int bid = blockIdx.x;
    const int xcd = bid & 7;
    const int idx = bid >> 3;                             // 0..63
    const int bm  = ((xcd >> 1) * 8 + (idx >> 3)) * 256;  // 32 row-tiles
    const int bn  = ((xcd & 1) * 8 + (idx & 7)) * 256;    // 16 col-tiles

    // staging: chunk c in [0,2048) per matrix; LDS addr c*16 (linear, required
    // by global_load_lds); content = logical quad q = (c&7) ^ (row&7) of row
    // c>>3 (XOR swizzle applied on the GLOBAL source address, LDS stays linear)
    uint32_t Aoff[4], Boff[4];
    int dL[4];
    #pragma unroll
    for (int s = 0; s < 4; ++s) {
        int c   = s * 512 + t;
        int row = c >> 3;
        int q   = (c & 7) ^ (row & 7);
        Aoff[s] = (uint32_t)(bm + row) * K_DIM + q * 16;
        Boff[s] = (uint32_t)(bn + row) * K_DIM + q * 16;
        dL[s]   = (s * 512 + wave * 64) * 16;   // wave-uniform; HW adds lane*16
    }

    // fragment reads: logical (r, q = h*4 + (lane>>4)) -> addr r*BK + (q^(r&7))*16
    // h=1 differs only in q bit 2 -> byte addr XOR 64.
    int aoff[8], boff[4];
    #pragma unroll
    for (int i = 0; i < 8; ++i) {
        int r = waveM * 128 + i * 16 + (lane & 15);
        aoff[i] = r * BK + (((lane >> 4) ^ (r & 7)) * 16);
    }
    #pragma unroll
    for (int j = 0; j < 4; ++j) {
        int r = waveN * 64 + j * 16 + (lane & 15);
        boff[j] = r * BK + (((lane >> 4) ^ (r & 7)) * 16);
    }

    i32x4 acc[8][4] = {};

#define STAGE(b, tt)                                                      \
    {                                                                     \
        _Pragma("unroll") for (int s = 0; s < 4; ++s)                     \
            cp16_async(X + Aoff[s] + (tt) * BK, &lds[b][0][dL[s]]);       \
        _Pragma("unroll") for (int s = 0; s < 4; ++s)                     \
            cp16_async(W + Boff[s] + (tt) * BK, &lds[b][1][dL[s]]);       \
    }

    // prologue: tiles 0 and 1 in flight; wait only for tile 0 (vmcnt(8)).
    STAGE(0, 0)
    STAGE(1, 1)
    asm volatile("s_waitcnt vmcnt(8)" ::: "memory");
    __builtin_amdgcn_s_barrier();

    // Per tile: [12 ds_read h0][32 MFMA h0][12 ds_read h1][lgkm0+bar]
    //           [stage tile tt+2][32 MFMA h1][vmcnt(8)+bar]
    // The vmcnt(8) waits on loads issued one full tile (~2600 cyc) earlier;
    // tile tt+2's 8 loads stay in flight across the barrier (T4).
#define TILE_STEP(b, tt)                                                  \
    {                                                                     \
        const int8_t* pA = &lds[b][0][0];                                 \
        const int8_t* pB = &lds[b][1][0];                                 \
        i32x4 af[8], bf[4];                                               \
        _Pragma("unroll") for (int i = 0; i < 8; ++i)                     \
            af[i] = *(const i32x4*)(pA + aoff[i]);                        \
        _Pragma("unroll") for (int j = 0; j < 4; ++j)                     \
            bf[j] = *(const i32x4*)(pB + boff[j]);                        \
        __builtin_amdgcn_s_setprio(1);                                    \
        _Pragma("unroll") for (int i = 0; i < 8; ++i)                     \
            _Pragma("unroll") for (int j = 0; j < 4; ++j)                 \
                acc[i][j] = __builtin_amdgcn_mfma_i32_16x16x64_i8(        \
                    af[i], bf[j], acc[i][j], 0, 0, 0);                    \
        __builtin_amdgcn_s_setprio(0);                                    \
        _Pragma("unroll") for (int i = 0; i < 8; ++i)                     \
            af[i] = *(const i32x4*)(pA + (aoff[i] ^ 64));                 \
        _Pragma("unroll") for (int j = 0; j < 4; ++j)                     \
            bf[j] = *(const i32x4*)(pB + (boff[j] ^ 64));                 \
        asm volatile("s_waitcnt lgkmcnt(0)" ::: "memory");                \
        __builtin_amdgcn_s_barrier();                                     \
        if ((tt) + 2 < NT) {                                              \
            STAGE(b, (tt) + 2)                                            \
            __builtin_amdgcn_sched_barrier(0);                            \
        }                                                                 \
        __builtin_amdgcn_s_setprio(1);                                    \
        _Pragma("unroll") for (int i = 0; i < 8; ++i)                     \
            _Pragma("unroll") for (int j = 0; j < 4; ++j)                 \
                acc[i][j] = __builtin_amdgcn_mfma_i32_16x16x64_i8(        \
                    af[i], bf[j], acc[i][j], 0, 0, 0);                    \
        __builtin_amdgcn_s_setprio(0);                                    \
        if ((tt) + 2 < NT) {                                              \
            asm volatile("s_waitcnt vmcnt(8)" ::: "memory");              \
        } else if ((tt) + 1 < NT) {                                       \
            asm volatile("s_waitcnt vmcnt(0)" ::: "memory");              \
        }                                                                 \
        if ((tt) + 1 < NT) __builtin_amdgcn_s_barrier();                  \
    }

    #pragma unroll
    for (int tp = 0; tp < NT; tp += 2) {
        TILE_STEP(0, tp)
        TILE_STEP(1, tp + 1)
    }

    // epilogue: C/D layout col=lane&15, row=(lane>>4)*4+reg
    const float si = scale_i[0];
    float sc[4], bi[4];
    int   ncol[4];
    #pragma unroll
    for (int j = 0; j < 4; ++j) {
        ncol[j] = bn + waveN * 64 + j * 16 + (lane & 15);
        sc[j] = si * scale_w[ncol[j]];
        bi[j] = bias[ncol[j]];
    }
    #pragma unroll
    for (int i = 0; i < 8; ++i) {
        int mbase = bm + waveM * 128 + i * 16 + ((lane >> 4) * 4);
        #pragma unroll
        for (int r = 0; r < 4; ++r) {
            size_t rowoff = (size_t)(mbase + r) * N_DIM;
            #pragma unroll
            for (int j = 0; j < 4; ++j) {
                out[rowoff + ncol[j]] = (float)acc[i][j][r] * sc[j] + bi[j];
            }
        }
    }
}

extern "C" void kernel_launch(void* const* d_in, const int* in_sizes, int n_in,
                              void* d_out, int out_size, void* d_ws, size_t ws_size,
                              hipStream_t stream) {
    const int* x32 = (const int*)d_in[0];   // [M,K] int32
    const int* w32 = (const int*)d_in[1];   // [N,K] int32
    const float* si = (const float*)d_in[2];
    const float* sw = (const float*)d_in[3];
    const float* bs = (const float*)d_in[4];
    float* out = (float*)d_out;

    int8_t* Xp = (int8_t*)d_ws;                              // 8 MB
    int8_t* Wp = (int8_t*)d_ws + (size_t)M_DIM * K_DIM;      // 4 MB

    // one fused pack launch: 2048 blocks for X + 1024 for W
    pack_both<<<3072, 256, 0, stream>>>(x32, w32, (int*)Xp, (int*)Wp);

    // 512 blocks = 32 x 16 tiles, XCD-swizzled in-kernel
    i8gemm_dequant<<<dim3(512), dim3(512), 0, stream>>>(Xp, Wp, si, sw, bs, out);
}

// Round 2
// 201.326 us; speedup vs baseline: 1.0021x; 1.0021x over previous
//
#include <hip/hip_runtime.h>
#include <stdint.h>

// out[b,s,n] = int32(sum_k x[b,s,k]*w[n,k]) * (scale_i*scale_w[n]) + bias[n]
// Inputs materialized as int32; pack to int8 in d_ws, then i8 MFMA GEMM.
// GEMM: 128x128 tile, BK=64, 4 waves (2x2), 32 KiB LDS double-buffer,
// depth-2 tile prefetch with counted vmcnt(4) (never drained mid-loop),
// raw s_barrier (no vmcnt drain), 3 blocks/CU co-residency for overlap.
#define M_DIM 8192
#define N_DIM 4096
#define K_DIM 1024
#define BK    64
#define NT    (K_DIM / BK)   // 16 K-tiles

using i32x4 = __attribute__((ext_vector_type(4))) int;

// ---- fused pack pass: int32 (low byte) -> int8, 16 ints per thread ----
// blocks [0, 2048): X (8.4M ints); blocks [2048, 3072): W (4.2M ints)
__global__ __launch_bounds__(256) void pack_both(const int* __restrict__ X32,
                                                 const int* __restrict__ W32,
                                                 int* __restrict__ Xp,
                                                 int* __restrict__ Wp) {
    int b = blockIdx.x;
    const int4* s4;
    int4* d4;
    int u;
    if (b < 2048) {            // X: 2097152 packed dwords / 4 per thread
        u  = b * 256 + threadIdx.x;
        s4 = (const int4*)X32;
        d4 = (int4*)Xp;
    } else {                   // W: 1048576 packed dwords / 4 per thread
        u  = (b - 2048) * 256 + threadIdx.x;
        s4 = (const int4*)W32;
        d4 = (int4*)Wp;
    }
    int4 o;
    #pragma unroll
    for (int i = 0; i < 4; ++i) {
        int4 v = s4[u * 4 + i];
        ((int*)&o)[i] = (v.x & 0xFF) | ((v.y & 0xFF) << 8) |
                        ((v.z & 0xFF) << 16) | (v.w << 24);
    }
    d4[u] = o;
}

// async global->LDS, 16B per lane. LDS dest is wave-uniform base + lane*16.
__device__ __forceinline__ void cp16_async(const void* g, void* l) {
    __builtin_amdgcn_global_load_lds(
        (const __attribute__((address_space(1))) void*)g,
        (__attribute__((address_space(3))) void*)l,
        16, 0, 0);
}

__global__ __launch_bounds__(256, 3) void i8gemm_dequant(
    const int8_t* __restrict__ X,        // [M, K] packed int8
    const int8_t* __restrict__ W,        // [N, K] packed int8
    const float*  __restrict__ scale_i,  // [1]
    const float*  __restrict__ scale_w,  // [N]
    const float*  __restrict__ bias,     // [N]
    float*        __restrict__ out)      // [M, N]
{
    // [buf][A|B][128 rows x 64 B] = 2*2*8 KB = 32 KiB
    __shared__ int8_t lds[2][2][128 * BK];

    const int t     = threadIdx.x;
    const int lane  = t & 63;
    const int wave  = t >> 6;      // 0..3
    const int waveM = wave >> 1;   // 0..1 -> 64-row half
    const int waveN = wave & 1;    // 0..1 -> 64-col half

    // 2D XCD-aware swizzle: 2048 blocks -> 8 XCDs, 16x16-tile chunk each
    // (2 MB of A rows + 2 MB of B rows fits the XCD's 4 MB L2).
    const int bid = blockIdx.x;
    const int xcd = bid & 7;
    const int idx = bid >> 3;                               // 0..255
    const int bm  = ((xcd >> 1) * 16 + (idx >> 4)) * 128;   // 64 row-tiles
    const int bn  = ((xcd & 1) * 16 + (idx & 15)) * 128;    // 32 col-tiles

    // staging: chunk c in [0,512) per matrix; LDS addr c*16 (linear, required
    // by global_load_lds); row = c>>2, holds logical quad q = (c&3)^(row&3)
    // (XOR swizzle applied on the GLOBAL source address, LDS stays linear)
    uint32_t Aoff[2], Boff[2];
    int dL[2];
    #pragma unroll
    for (int s = 0; s < 2; ++s) {
        int c   = s * 256 + t;
        int row = c >> 2;
        int q   = (c & 3) ^ (row & 3);
        Aoff[s] = (uint32_t)(bm + row) * K_DIM + q * 16;
        Boff[s] = (uint32_t)(bn + row) * K_DIM + q * 16;
        dL[s]   = (s * 256 + wave * 64) * 16;   // wave-uniform; HW adds lane*16
    }

    // fragment reads: logical (r, q=lane>>4) -> addr r*BK + ((lane>>4)^(r&3))*16
    int aoff[4], boff[4];
    #pragma unroll
    for (int i = 0; i < 4; ++i) {
        int r = waveM * 64 + i * 16 + (lane & 15);
        aoff[i] = r * BK + (((lane >> 4) ^ (r & 3)) * 16);
    }
    #pragma unroll
    for (int j = 0; j < 4; ++j) {
        int r = waveN * 64 + j * 16 + (lane & 15);
        boff[j] = r * BK + (((lane >> 4) ^ (r & 3)) * 16);
    }

    i32x4 acc[4][4] = {};

#define STAGE(b, tt)                                                      \
    {                                                                     \
        _Pragma("unroll") for (int s = 0; s < 2; ++s)                     \
            cp16_async(X + Aoff[s] + (tt) * BK, &lds[b][0][dL[s]]);       \
        _Pragma("unroll") for (int s = 0; s < 2; ++s)                     \
            cp16_async(W + Boff[s] + (tt) * BK, &lds[b][1][dL[s]]);       \
    }

    // prologue: tiles 0 and 1 in flight; wait only for tile 0 (vmcnt(4)).
    STAGE(0, 0)
    STAGE(1, 1)
    asm volatile("s_waitcnt vmcnt(4)" ::: "memory");
    __builtin_amdgcn_s_barrier();

    // Per tile: [8 ds_read][lgkm0 + bar: all waves done with buf b]
    //           [STAGE tt+2 into buf b][16 MFMA][vmcnt(4) + bar: tile tt+1 ready]
    // vmcnt(4) waits on loads issued one full tile earlier; tile tt+2's 4
    // loads stay in flight across the barrier (T4, never drain mid-loop).
#define TILE_STEP(b, tt)                                                  \
    {                                                                     \
        const int8_t* pA = &lds[b][0][0];                                 \
        const int8_t* pB = &lds[b][1][0];                                 \
        i32x4 af[4], bf[4];                                               \
        _Pragma("unroll") for (int i = 0; i < 4; ++i)                     \
            af[i] = *(const i32x4*)(pA + aoff[i]);                        \
        _Pragma("unroll") for (int j = 0; j < 4; ++j)                     \
            bf[j] = *(const i32x4*)(pB + boff[j]);                        \
        asm volatile("s_waitcnt lgkmcnt(0)" ::: "memory");                \
        __builtin_amdgcn_s_barrier();                                     \
        if ((tt) + 2 < NT) {                                              \
            STAGE(b, (tt) + 2)                                            \
            __builtin_amdgcn_sched_barrier(0);                            \
        }                                                                 \
        __builtin_amdgcn_s_setprio(1);                                    \
        _Pragma("unroll") for (int i = 0; i < 4; ++i)                     \
            _Pragma("unroll") for (int j = 0; j < 4; ++j)                 \
                acc[i][j] = __builtin_amdgcn_mfma_i32_16x16x64_i8(        \
                    af[i], bf[j], acc[i][j], 0, 0, 0);                    \
        __builtin_amdgcn_s_setprio(0);                                    \
        if ((tt) + 2 < NT) {                                              \
            asm volatile("s_waitcnt vmcnt(4)" ::: "memory");              \
        } else if ((tt) + 1 < NT) {                                       \
            asm volatile("s_waitcnt vmcnt(0)" ::: "memory");              \
        }                                                                 \
        if ((tt) + 1 < NT) __builtin_amdgcn_s_barrier();                  \
    }

    #pragma unroll
    for (int tp = 0; tp < NT; tp += 2) {
        TILE_STEP(0, tp)
        TILE_STEP(1, tp + 1)
    }

    // epilogue: C/D layout col=lane&15, row=(lane>>4)*4+reg
    const float si = scale_i[0];
    float sc[4], bi[4];
    int   ncol[4];
    #pragma unroll
    for (int j = 0; j < 4; ++j) {
        ncol[j] = bn + waveN * 64 + j * 16 + (lane & 15);
        sc[j] = si * scale_w[ncol[j]];
        bi[j] = bias[ncol[j]];
    }
    #pragma unroll
    for (int i = 0; i < 4; ++i) {
        int mbase = bm + waveM * 64 + i * 16 + ((lane >> 4) * 4);
        #pragma unroll
        for (int r = 0; r < 4; ++r) {
            size_t rowoff = (size_t)(mbase + r) * N_DIM;
            #pragma unroll
            for (int j = 0; j < 4; ++j) {
                out[rowoff + ncol[j]] = (float)acc[i][j][r] * sc[j] + bi[j];
            }
        }
    }
}

extern "C" void kernel_launch(void* const* d_in, const int* in_sizes, int n_in,
                              void* d_out, int out_size, void* d_ws, size_t ws_size,
                              hipStream_t stream) {
    const int* x32 = (const int*)d_in[0];   // [M,K] int32
    const int* w32 = (const int*)d_in[1];   // [N,K] int32
    const float* si = (const float*)d_in[2];
    const float* sw = (const float*)d_in[3];
    const float* bs = (const float*)d_in[4];
    float* out = (float*)d_out;

    int8_t* Xp = (int8_t*)d_ws;                              // 8 MB
    int8_t* Wp = (int8_t*)d_ws + (size_t)M_DIM * K_DIM;      // 4 MB

    // one fused pack launch: 2048 blocks for X + 1024 for W
    pack_both<<<3072, 256, 0, stream>>>(x32, w32, (int*)Xp, (int*)Wp);

    // 2048 blocks = 64 x 32 tiles, XCD-swizzled in-kernel
    i8gemm_dequant<<<dim3(2048), dim3(256), 0, stream>>>(Xp, Wp, si, sw, bs, out);
}

// Round 3
// 200.211 us; speedup vs baseline: 1.0077x; 1.0056x over previous
//
#include <hip/hip_runtime.h>
#include <stdint.h>

// out[b,s,n] = int32(sum_k x[b,s,k]*w[n,k]) * (scale_i*scale_w[n]) + bias[n]
// Inputs materialized as int32; pack to int8 in d_ws, then i8 MFMA GEMM.
// GEMM: 128x128 tile, BK=64, 4 waves (2x2), 32 KiB LDS double-buffer,
// depth-2 tile prefetch with counted vmcnt(4) (never drained mid-loop),
// raw s_barrier (no vmcnt drain), 4 blocks/CU co-residency for write overlap.
// Pack: fully-coalesced stride-256 int4 loads (1 KB/wave-instruction).
#define M_DIM 8192
#define N_DIM 4096
#define K_DIM 1024
#define BK    64
#define NT    (K_DIM / BK)   // 16 K-tiles

using i32x4 = __attribute__((ext_vector_type(4))) int;

// ---- fused pack pass: int32 (low byte) -> int8, 16 ints per thread ----
// blocks [0, 2048): X (8.4M ints); blocks [2048, 3072): W (4.2M ints)
// Coalesced: thread t of block b handles int4-chunks base + i*256 + t, so each
// load/store instruction is wave-contiguous (64 lanes x 16B = 1 KB reads).
__global__ __launch_bounds__(256) void pack_both(const int* __restrict__ X32,
                                                 const int* __restrict__ W32,
                                                 int* __restrict__ Xp,
                                                 int* __restrict__ Wp) {
    int b = blockIdx.x;
    const int4* s4;
    int* d;
    int base;
    if (b < 2048) {            // X: 2097152 int4-chunks, 1024 per block
        base = b * 1024;
        s4   = (const int4*)X32;
        d    = (int*)Xp;
    } else {                   // W: 1048576 int4-chunks, 1024 per block
        base = (b - 2048) * 1024;
        s4   = (const int4*)W32;
        d    = (int*)Wp;
    }
    #pragma unroll
    for (int i = 0; i < 4; ++i) {
        int g = base + i * 256 + threadIdx.x;
        int4 v = s4[g];
        d[g] = (v.x & 0xFF) | ((v.y & 0xFF) << 8) |
               ((v.z & 0xFF) << 16) | (v.w << 24);
    }
}

// async global->LDS, 16B per lane. LDS dest is wave-uniform base + lane*16.
__device__ __forceinline__ void cp16_async(const void* g, void* l) {
    __builtin_amdgcn_global_load_lds(
        (const __attribute__((address_space(1))) void*)g,
        (__attribute__((address_space(3))) void*)l,
        16, 0, 0);
}

__global__ __launch_bounds__(256, 4) void i8gemm_dequant(
    const int8_t* __restrict__ X,        // [M, K] packed int8
    const int8_t* __restrict__ W,        // [N, K] packed int8
    const float*  __restrict__ scale_i,  // [1]
    const float*  __restrict__ scale_w,  // [N]
    const float*  __restrict__ bias,     // [N]
    float*        __restrict__ out)      // [M, N]
{
    // [buf][A|B][128 rows x 64 B] = 2*2*8 KB = 32 KiB -> 4 blocks/CU
    __shared__ int8_t lds[2][2][128 * BK];

    const int t     = threadIdx.x;
    const int lane  = t & 63;
    const int wave  = t >> 6;      // 0..3
    const int waveM = wave >> 1;   // 0..1 -> 64-row half
    const int waveN = wave & 1;    // 0..1 -> 64-col half

    // 2D XCD-aware swizzle: 2048 blocks -> 8 XCDs, 16x16-tile chunk each
    // (2 MB of A rows + 2 MB of B rows fits the XCD's 4 MB L2).
    const int bid = blockIdx.x;
    const int xcd = bid & 7;
    const int idx = bid >> 3;                               // 0..255
    const int bm  = ((xcd >> 1) * 16 + (idx >> 4)) * 128;   // 64 row-tiles
    const int bn  = ((xcd & 1) * 16 + (idx & 15)) * 128;    // 32 col-tiles

    // staging: chunk c in [0,512) per matrix; LDS addr c*16 (linear, required
    // by global_load_lds); row = c>>2, holds logical quad q = (c&3)^(row&3)
    // (XOR swizzle applied on the GLOBAL source address, LDS stays linear)
    uint32_t Aoff[2], Boff[2];
    int dL[2];
    #pragma unroll
    for (int s = 0; s < 2; ++s) {
        int c   = s * 256 + t;
        int row = c >> 2;
        int q   = (c & 3) ^ (row & 3);
        Aoff[s] = (uint32_t)(bm + row) * K_DIM + q * 16;
        Boff[s] = (uint32_t)(bn + row) * K_DIM + q * 16;
        dL[s]   = (s * 256 + wave * 64) * 16;   // wave-uniform; HW adds lane*16
    }

    // fragment reads: logical (r, q=lane>>4) -> addr r*BK + ((lane>>4)^(r&3))*16
    int aoff[4], boff[4];
    #pragma unroll
    for (int i = 0; i < 4; ++i) {
        int r = waveM * 64 + i * 16 + (lane & 15);
        aoff[i] = r * BK + (((lane >> 4) ^ (r & 3)) * 16);
    }
    #pragma unroll
    for (int j = 0; j < 4; ++j) {
        int r = waveN * 64 + j * 16 + (lane & 15);
        boff[j] = r * BK + (((lane >> 4) ^ (r & 3)) * 16);
    }

    i32x4 acc[4][4] = {};

#define STAGE(b, tt)                                                      \
    {                                                                     \
        _Pragma("unroll") for (int s = 0; s < 2; ++s)                     \
            cp16_async(X + Aoff[s] + (tt) * BK, &lds[b][0][dL[s]]);       \
        _Pragma("unroll") for (int s = 0; s < 2; ++s)                     \
            cp16_async(W + Boff[s] + (tt) * BK, &lds[b][1][dL[s]]);       \
    }

    // prologue: tiles 0 and 1 in flight; wait only for tile 0 (vmcnt(4)).
    STAGE(0, 0)
    STAGE(1, 1)
    asm volatile("s_waitcnt vmcnt(4)" ::: "memory");
    __builtin_amdgcn_s_barrier();

    // Per tile: [8 ds_read][lgkm0 + bar: all waves done with buf b]
    //           [STAGE tt+2 into buf b][16 MFMA][vmcnt(4) + bar: tile tt+1 ready]
    // vmcnt(4) waits on loads issued one full tile earlier; tile tt+2's 4
    // loads stay in flight across the barrier (T4, never drain mid-loop).
#define TILE_STEP(b, tt)                                                  \
    {                                                                     \
        const int8_t* pA = &lds[b][0][0];                                 \
        const int8_t* pB = &lds[b][1][0];                                 \
        i32x4 af[4], bf[4];                                               \
        _Pragma("unroll") for (int i = 0; i < 4; ++i)                     \
            af[i] = *(const i32x4*)(pA + aoff[i]);                        \
        _Pragma("unroll") for (int j = 0; j < 4; ++j)                     \
            bf[j] = *(const i32x4*)(pB + boff[j]);                        \
        asm volatile("s_waitcnt lgkmcnt(0)" ::: "memory");                \
        __builtin_amdgcn_s_barrier();                                     \
        if ((tt) + 2 < NT) {                                              \
            STAGE(b, (tt) + 2)                                            \
            __builtin_amdgcn_sched_barrier(0);                            \
        }                                                                 \
        __builtin_amdgcn_s_setprio(1);                                    \
        _Pragma("unroll") for (int i = 0; i < 4; ++i)                     \
            _Pragma("unroll") for (int j = 0; j < 4; ++j)                 \
                acc[i][j] = __builtin_amdgcn_mfma_i32_16x16x64_i8(        \
                    af[i], bf[j], acc[i][j], 0, 0, 0);                    \
        __builtin_amdgcn_s_setprio(0);                                    \
        if ((tt) + 2 < NT) {                                              \
            asm volatile("s_waitcnt vmcnt(4)" ::: "memory");              \
        } else if ((tt) + 1 < NT) {                                       \
            asm volatile("s_waitcnt vmcnt(0)" ::: "memory");              \
        }                                                                 \
        if ((tt) + 1 < NT) __builtin_amdgcn_s_barrier();                  \
    }

    #pragma unroll
    for (int tp = 0; tp < NT; tp += 2) {
        TILE_STEP(0, tp)
        TILE_STEP(1, tp + 1)
    }

    // epilogue: C/D layout col=lane&15, row=(lane>>4)*4+reg
    const float si = scale_i[0];
    float sc[4], bi[4];
    int   ncol[4];
    #pragma unroll
    for (int j = 0; j < 4; ++j) {
        ncol[j] = bn + waveN * 64 + j * 16 + (lane & 15);
        sc[j] = si * scale_w[ncol[j]];
        bi[j] = bias[ncol[j]];
    }
    #pragma unroll
    for (int i = 0; i < 4; ++i) {
        int mbase = bm + waveM * 64 + i * 16 + ((lane >> 4) * 4);
        #pragma unroll
        for (int r = 0; r < 4; ++r) {
            size_t rowoff = (size_t)(mbase + r) * N_DIM;
            #pragma unroll
            for (int j = 0; j < 4; ++j) {
                out[rowoff + ncol[j]] = (float)acc[i][j][r] * sc[j] + bi[j];
            }
        }
    }
}

extern "C" void kernel_launch(void* const* d_in, const int* in_sizes, int n_in,
                              void* d_out, int out_size, void* d_ws, size_t ws_size,
                              hipStream_t stream) {
    const int* x32 = (const int*)d_in[0];   // [M,K] int32
    const int* w32 = (const int*)d_in[1];   // [N,K] int32
    const float* si = (const float*)d_in[2];
    const float* sw = (const float*)d_in[3];
    const float* bs = (const float*)d_in[4];
    float* out = (float*)d_out;

    int8_t* Xp = (int8_t*)d_ws;                              // 8 MB
    int8_t* Wp = (int8_t*)d_ws + (size_t)M_DIM * K_DIM;      // 4 MB

    // one fused pack launch: 2048 blocks for X + 1024 for W
    pack_both<<<3072, 256, 0, stream>>>(x32, w32, (int*)Xp, (int*)Wp);

    // 2048 blocks = 64 x 32 tiles, XCD-swizzled in-kernel
    i8gemm_dequant<<<dim3(2048), dim3(256), 0, stream>>>(Xp, Wp, si, sw, bs, out);
}